// Round 6
// baseline (712.699 us; speedup 1.0000x reference)
//
#include <hip/hip_runtime.h>

#define NN 50000
#define DD 64
#define EE 800000
#define BB 50
#define NMAXX 1000
#define CC 100

#define NBKT 391      // ceil(NN/128): bucket = dst>>7, owns 128 dst rows
#define BCAP 3072     // bucket capacity; mean 2048, sigma~45 -> >20 sigma + guard

typedef short short8 __attribute__((ext_vector_type(8)));
typedef float float4v __attribute__((ext_vector_type(4)));

__device__ __forceinline__ float rl(float v, int l) {
  return __int_as_float(__builtin_amdgcn_readlane(__float_as_int(v), l));
}
__device__ __forceinline__ short f2bf(float f) {
  unsigned u = __float_as_uint(f);
  unsigned r = (u + 0x7fffu + ((u >> 16) & 1u)) >> 16;
  return (short)r;
}
__device__ __forceinline__ unsigned pack2(float a, float b) {
  return (unsigned)(unsigned short)f2bf(a) |
         ((unsigned)(unsigned short)f2bf(b) << 16);
}

// B-fragment index for 16x16x32: frag[((ks*4+cb)*64+lane)*8+j] = W[k][n]
// k = ks*32 + (lane>>4)*8 + j, n = cb*16 + (lane&15)

// ---------- prep (fused): bucket-append edges + x->bf16 + W packs + msgup ----------
__global__ __launch_bounds__(256) void k_prep(
    const int* __restrict__ ei, const float* __restrict__ x,
    const float* __restrict__ attr1,
    const float* __restrict__ Wma, const float* __restrict__ Wmu,
    const float* __restrict__ bmu, const float* __restrict__ Wua,
    const float* __restrict__ Wuu, const float* __restrict__ Wc,
    int* __restrict__ bcnt, short* __restrict__ xb,
    uint2* __restrict__ sdeB, short* __restrict__ msgupT,
    short* __restrict__ WtF, short* __restrict__ WtF1,
    short* __restrict__ WtF2, short* __restrict__ WtF3) {
  const int tid = threadIdx.x;
  if (blockIdx.x < EE / 256) {
    const int i = blockIdx.x * 256 + tid;          // [0, 800000)
    const int s = ei[i];
    const int d = ei[EE + i];
    const int bkt = d >> 7;                        // 0..390
    int pos = atomicAdd(&bcnt[bkt * 16], 1);       // 64B-padded counters
    if (pos < BCAP)
      sdeB[(size_t)bkt * BCAP + pos] =
          make_uint2((unsigned)s | ((unsigned)d << 16), (unsigned)i);
    {
      // NN*16 == EE: every thread converts 4 floats -> 4 bf16 (8B store)
      float4 xv = *(const float4*)&x[(size_t)i * 4];
      ((uint2*)xb)[i] = make_uint2(pack2(xv.x, xv.y), pack2(xv.z, xv.w));
    }
    if (i < 8192) {
      int j = i & 7, lane = (i >> 3) & 63, cbks = i >> 9;
      int cb = cbks & 3, ks = cbks >> 2;
      int k = ks * 32 + (lane >> 4) * 8 + j;
      int n = cb * 16 + (lane & 15);
      WtF[i]  = f2bf(Wma[k * 64 + n]);   // K=128
      WtF3[i] = f2bf(Wc[k * 64 + n]);    // K=128
      if (i < 4096) {                    // K=64 mats
        WtF1[i] = f2bf(Wua[k * 64 + n]);
        WtF2[i] = f2bf(Wuu[k * 64 + n]);
      }
    }
  } else {
    // ---- msgup branch ----
    __shared__ float Wl[64 * 64];
    for (int i = tid; i < 64 * 64; i += 256) Wl[i] = Wmu[i];
    __syncthreads();
    const int lane = tid & 63;
    const int row = (blockIdx.x - EE / 256) * 4 + (tid >> 6);   // b*100 + c
    float a = attr1[(size_t)row * 64 + lane];
    float acc = bmu[lane];
#pragma unroll 8
    for (int k = 0; k < 64; ++k)
      acc = fmaf(rl(a, k), Wl[k * 64 + lane], acc);
    const int b = row / 100, c = row - b * 100;
    msgupT[(size_t)b * 6400 + lane * 100 + c] = f2bf(fmaxf(acc, 0.f));
  }
}

// ---------- K2 (MFMA): agg_up = nc1 @ msg_up ----------
__global__ __launch_bounds__(256) void k_aggup(
    const float* __restrict__ nc1, const short* __restrict__ msgupT,
    float* __restrict__ aggup) {
  constexpr int LDA = 136;
  __shared__ float Ncf[64 * CC];
  __shared__ short A[64 * LDA];
  __shared__ short Wt[64 * LDA];
  const int b = blockIdx.x >> 4;
  const int tile = blockIdx.x & 15;
  const int i0 = tile * 64;
  const int tid = threadIdx.x;
  const float* ncb = nc1 + ((size_t)b * NMAXX + i0) * CC;
  for (int idx = tid; idx < 64 * CC; idx += 256) {
    int r = idx / CC;
    Ncf[idx] = (i0 + r < NMAXX) ? ncb[idx] : 0.f;
  }
  {
    const unsigned* src = (const unsigned*)(msgupT + (size_t)b * 6400);
    unsigned* dstw = (unsigned*)Wt;
    for (int i = tid; i < 64 * 50; i += 256) {
      int row = i / 50, cu = i - row * 50;
      dstw[row * 68 + cu] = src[i];
    }
    for (int i = tid; i < 64 * 14; i += 256) {
      int row = i / 14, cu = 50 + (i - row * 14);
      dstw[row * 68 + cu] = 0;
    }
  }
  __syncthreads();
  {
    const int row = tid >> 2, kp = tid & 3;
#pragma unroll
    for (int j = 0; j < 16; ++j) {
      int k = kp * 32 + 2 * j;
      unsigned u = 0;
      if (k < CC) {
        float2 v = *(const float2*)&Ncf[row * CC + k];
        u = pack2(v.x, v.y);
      }
      *(unsigned*)&A[row * LDA + k] = u;
    }
  }
  __syncthreads();
  const int lane = tid & 63;
  const int w = tid >> 6;
  const int m = lane & 15;
  const int koff = (lane >> 4) * 8;
  float4v acc[4];
#pragma unroll
  for (int cb = 0; cb < 4; ++cb) acc[cb] = (float4v)0.f;
#pragma unroll
  for (int ks = 0; ks < 4; ++ks) {
    short8 af = *(const short8*)&A[(w * 16 + m) * LDA + ks * 32 + koff];
#pragma unroll
    for (int cb = 0; cb < 4; ++cb) {
      short8 bf = *(const short8*)&Wt[(cb * 16 + m) * LDA + ks * 32 + koff];
      acc[cb] = __builtin_amdgcn_mfma_f32_16x16x32_bf16(af, bf, acc[cb], 0, 0, 0);
    }
  }
  const int rbase = (lane >> 4) * 4;
#pragma unroll
  for (int cb = 0; cb < 4; ++cb)
#pragma unroll
    for (int r = 0; r < 4; ++r) {
      int i = i0 + w * 16 + rbase + r;
      if (i < NMAXX)
        aggup[((size_t)b * NMAXX + i) * 64 + cb * 16 + m] = acc[cb][r];
    }
}

// ---------- K3 (MFMA): bucket-owned edge MLP + LDS accumulation ----------
// block = bucket b (dst in [128b, 128b+128)), 512 threads = 8 waves.
// Edges consumed UNSORTED from sdeB; per-chunk MFMA msgs accumulate into a
// 128x64 LDS tile via ds_add_f32; final plain coalesced agg stores.
// No sort, no global atomics, no agg memset.
__global__ __launch_bounds__(512) void k_edge_bkt(
    const short* __restrict__ xb, const float* __restrict__ e,
    const uint2* __restrict__ sdeB, const int* __restrict__ bcnt,
    const short* __restrict__ WtF, const float* __restrict__ bma,
    float* __restrict__ agg) {
  constexpr int AS = 66;             // Acc stride: 2-way bank alias only (free)
  __shared__ short WtL[8192];        // 16 KB fragment-ordered W_ma
  __shared__ float Acc[128 * AS];    // 33.8 KB
  const int tid = threadIdx.x;
  const int b = blockIdx.x;
  {
    const uint4* s = (const uint4*)WtF;
    uint4* d = (uint4*)WtL;
    d[tid] = s[tid];
    d[512 + tid] = s[512 + tid];
  }
  for (int i = tid; i < 128 * AS; i += 512) Acc[i] = 0.f;
  __syncthreads();
  const int lane = tid & 63;
  const int wv = tid >> 6;           // 0..7
  const int m = lane & 15;
  const int koff = (lane >> 4) * 8;
  const int rbase = (lane >> 4) * 4;
  float bias[4];
#pragma unroll
  for (int cb = 0; cb < 4; ++cb) bias[cb] = bma[cb * 16 + m];
  int n = bcnt[b * 16];
  if (n > BCAP) n = BCAP;
  const uint2* eb = sdeB + (size_t)b * BCAP;
  const int nch = (n + 15) >> 4;
  for (int c = wv; c < nch; c += 8) {
    const int c0 = c * 16;
    int idx = c0 + m;
    if (idx >= n) idx = n - 1;
    const uint2 v = eb[idx];
    const int src = (int)(v.x & 0xffffu);
    short8 a0 = *(const short8*)(xb + (size_t)src * 64 + koff);
    short8 a1 = *(const short8*)(xb + (size_t)src * 64 + 32 + koff);
    const float* er = e + (size_t)v.y * 64 + koff;
    float4 f0 = *(const float4*)er;
    float4 f1 = *(const float4*)(er + 4);
    float4 f2 = *(const float4*)(er + 32);
    float4 f3 = *(const float4*)(er + 36);
    union { unsigned u[4]; short8 s; } p2, p3;
    p2.u[0] = pack2(f0.x, f0.y); p2.u[1] = pack2(f0.z, f0.w);
    p2.u[2] = pack2(f1.x, f1.y); p2.u[3] = pack2(f1.z, f1.w);
    p3.u[0] = pack2(f2.x, f2.y); p3.u[1] = pack2(f2.z, f2.w);
    p3.u[2] = pack2(f3.x, f3.y); p3.u[3] = pack2(f3.z, f3.w);
    float4v acc[4];
#pragma unroll
    for (int cb = 0; cb < 4; ++cb) {
      acc[cb] = (float4v)(bias[cb]);   // bias as MFMA C-in
      short8 b0 = *(const short8*)&WtL[((0 * 4 + cb) * 64 + lane) * 8];
      short8 b1 = *(const short8*)&WtL[((1 * 4 + cb) * 64 + lane) * 8];
      short8 b2 = *(const short8*)&WtL[((2 * 4 + cb) * 64 + lane) * 8];
      short8 b3 = *(const short8*)&WtL[((3 * 4 + cb) * 64 + lane) * 8];
      acc[cb] = __builtin_amdgcn_mfma_f32_16x16x32_bf16(a0, b0, acc[cb], 0, 0, 0);
      acc[cb] = __builtin_amdgcn_mfma_f32_16x16x32_bf16(a1, b1, acc[cb], 0, 0, 0);
      acc[cb] = __builtin_amdgcn_mfma_f32_16x16x32_bf16(p2.s, b2, acc[cb], 0, 0, 0);
      acc[cb] = __builtin_amdgcn_mfma_f32_16x16x32_bf16(p3.s, b3, acc[cb], 0, 0, 0);
    }
    const int dstv = (int)(v.x >> 16);
    int drs[4]; bool oks[4];
#pragma unroll
    for (int r = 0; r < 4; ++r) {
      drs[r] = __shfl(dstv, rbase + r) & 127;   // in-bucket row of edge rbase+r
      oks[r] = (c0 + rbase + r) < n;
    }
#pragma unroll
    for (int cb = 0; cb < 4; ++cb)
#pragma unroll
      for (int r = 0; r < 4; ++r)
        if (oks[r])
          atomicAdd(&Acc[drs[r] * AS + cb * 16 + m], fmaxf(acc[cb][r], 0.f));
  }
  __syncthreads();
  // coalesced writeout: 128 rows x 64 dims
  const int row0 = b << 7;
  for (int i = tid; i < 2048; i += 512) {
    const int row = i >> 4, sg = (i & 15) * 4;
    const int g = row0 + row;
    if (g < NN) {
      float* dp = &agg[(size_t)g * 64 + sg];
      const float* sp = &Acc[row * AS + sg];
      dp[0] = sp[0]; dp[1] = sp[1]; dp[2] = sp[2]; dp[3] = sp[3];
    }
  }
}

// ---------- K4 (MFMA): fused epilogue, B-frags direct from global ----------
__global__ __launch_bounds__(256) void k_final(
    const float* __restrict__ x, const float* __restrict__ agg,
    const float* __restrict__ aggup, const int* __restrict__ xidx,
    const float* __restrict__ eps1, const float* __restrict__ eps2,
    const short* __restrict__ WtF1, const float* __restrict__ bua,
    const short* __restrict__ WtF2, const float* __restrict__ buu,
    const short* __restrict__ WtF3, const float* __restrict__ bc,
    float* __restrict__ out) {
  constexpr int LD1 = 72;
  constexpr int LD3 = 136;
  __shared__ short A1[64 * LD1];
  __shared__ short A2[64 * LD1];
  __shared__ short O[64 * LD3];
  const int tid = threadIdx.x;
  const float s1 = 1.f + eps1[0], s2 = 1.f + eps2[0];
  const int r0 = blockIdx.x * 64;
  {
    const int row = tid >> 2, kp = tid & 3;
    int g = r0 + row;
    if (g >= NN) g = NN - 1;
    const size_t xb_ = (size_t)g * 64 + kp * 16;
    const size_t ub = (size_t)xidx[g] * 64 + kp * 16;
#pragma unroll
    for (int j = 0; j < 4; ++j) {
      float4 xv = *(const float4*)&x[xb_ + j * 4];
      float4 av = *(const float4*)&agg[xb_ + j * 4];
      float4 uv = *(const float4*)&aggup[ub + j * 4];
      unsigned h1lo = pack2(av.x + s1 * xv.x, av.y + s1 * xv.y);
      unsigned h1hi = pack2(av.z + s1 * xv.z, av.w + s1 * xv.w);
      unsigned h2lo = pack2(uv.x + s2 * xv.x, uv.y + s2 * xv.y);
      unsigned h2hi = pack2(uv.z + s2 * xv.z, uv.w + s2 * xv.w);
      *(uint2*)&A1[row * LD1 + kp * 16 + j * 4] = make_uint2(h1lo, h1hi);
      *(uint2*)&A2[row * LD1 + kp * 16 + j * 4] = make_uint2(h2lo, h2hi);
    }
  }
  __syncthreads();
  const int lane = tid & 63;
  const int w = tid >> 6;
  const int m = lane & 15;
  const int koff = (lane >> 4) * 8;
  const int rbase = (lane >> 4) * 4;
  float4v acc1[4], acc2[4];
#pragma unroll
  for (int cb = 0; cb < 4; ++cb) { acc1[cb] = (float4v)0.f; acc2[cb] = (float4v)0.f; }
#pragma unroll
  for (int ks = 0; ks < 2; ++ks) {
    short8 a1 = *(const short8*)&A1[(w * 16 + m) * LD1 + ks * 32 + koff];
    short8 a2 = *(const short8*)&A2[(w * 16 + m) * LD1 + ks * 32 + koff];
#pragma unroll
    for (int cb = 0; cb < 4; ++cb) {
      short8 b1 = *(const short8*)&WtF1[((ks * 4 + cb) * 64 + lane) * 8];
      short8 b2 = *(const short8*)&WtF2[((ks * 4 + cb) * 64 + lane) * 8];
      acc1[cb] = __builtin_amdgcn_mfma_f32_16x16x32_bf16(a1, b1, acc1[cb], 0, 0, 0);
      acc2[cb] = __builtin_amdgcn_mfma_f32_16x16x32_bf16(a2, b2, acc2[cb], 0, 0, 0);
    }
  }
#pragma unroll
  for (int cb = 0; cb < 4; ++cb) {
    float bb1 = bua[cb * 16 + m];
    float bb2 = buu[cb * 16 + m];
#pragma unroll
    for (int r = 0; r < 4; ++r) {
      int rowL = w * 16 + rbase + r;
      O[rowL * LD3 + cb * 16 + m] = f2bf(fmaxf(acc1[cb][r] + bb1, 0.f));
      O[rowL * LD3 + 64 + cb * 16 + m] = f2bf(fmaxf(acc2[cb][r] + bb2, 0.f));
    }
  }
  __syncthreads();
  float4v acc3[4];
#pragma unroll
  for (int cb = 0; cb < 4; ++cb) acc3[cb] = (float4v)0.f;
#pragma unroll
  for (int ks = 0; ks < 4; ++ks) {
    short8 af = *(const short8*)&O[(w * 16 + m) * LD3 + ks * 32 + koff];
#pragma unroll
    for (int cb = 0; cb < 4; ++cb) {
      short8 bf = *(const short8*)&WtF3[((ks * 4 + cb) * 64 + lane) * 8];
      acc3[cb] = __builtin_amdgcn_mfma_f32_16x16x32_bf16(af, bf, acc3[cb], 0, 0, 0);
    }
  }
#pragma unroll
  for (int cb = 0; cb < 4; ++cb) {
    float bb = bc[cb * 16 + m];
#pragma unroll
    for (int r = 0; r < 4; ++r) {
      int g = r0 + w * 16 + rbase + r;
      if (g < NN)
        out[(size_t)g * 64 + cb * 16 + m] = acc3[cb][r] + bb;
    }
  }
}

extern "C" void kernel_launch(void* const* d_in, const int* in_sizes, int n_in,
                              void* d_out, int out_size, void* d_ws, size_t ws_size,
                              hipStream_t stream) {
  const float* x     = (const float*)d_in[0];
  const float* e     = (const float*)d_in[1];
  const int*   ei    = (const int*)d_in[2];
  const float* attr1 = (const float*)d_in[3];
  const float* nc1   = (const float*)d_in[4];
  const int*   xidx  = (const int*)d_in[5];
  const float* eps1  = (const float*)d_in[6];
  const float* eps2  = (const float*)d_in[7];
  const float* Wma   = (const float*)d_in[8];
  const float* bma   = (const float*)d_in[9];
  const float* Wmu   = (const float*)d_in[10];
  const float* bmu   = (const float*)d_in[11];
  const float* Wua   = (const float*)d_in[12];
  const float* bua   = (const float*)d_in[13];
  const float* Wuu   = (const float*)d_in[14];
  const float* buu   = (const float*)d_in[15];
  const float* Wc    = (const float*)d_in[16];
  const float* bc    = (const float*)d_in[17];
  float* out = (float*)d_out;

  float* agg    = (float*)d_ws;                      // [N*64] f32 (fully written by k_edge_bkt)
  int*   bcnt   = (int*)(agg + (size_t)NN * 64);     // [NBKT*16] (memset)
  float* aggup  = (float*)(bcnt + NBKT * 16);        // [N*64] f32
  short* msgupT = (short*)(aggup + (size_t)NN * 64); // [B*64*100] bf16
  short* xbuf   = msgupT + (size_t)BB * 6400;        // [N*64] bf16
  uint2* sdeB   = (uint2*)(xbuf + (size_t)NN * 64);  // [NBKT*BCAP] bucketed
  short* WtF    = (short*)(sdeB + (size_t)NBKT * BCAP); // [8192]
  short* WtF1   = WtF + 8192;                        // [4096]
  short* WtF2   = WtF1 + 4096;                       // [4096]
  short* WtF3   = WtF2 + 4096;                       // [8192]

  hipMemsetAsync(bcnt, 0, NBKT * 16 * sizeof(int), stream);
  k_prep<<<dim3(EE / 256 + BB * CC / 4), dim3(256), 0, stream>>>(
      ei, x, attr1, Wma, Wmu, bmu, Wua, Wuu, Wc,
      bcnt, xbuf, sdeB, msgupT, WtF, WtF1, WtF2, WtF3);
  k_aggup<<<dim3(BB * 16), dim3(256), 0, stream>>>(nc1, msgupT, aggup);
  k_edge_bkt<<<dim3(NBKT), dim3(512), 0, stream>>>(
      xbuf, e, sdeB, bcnt, WtF, bma, agg);
  k_final<<<dim3((NN + 63) / 64), dim3(256), 0, stream>>>(
      x, agg, aggup, xidx, eps1, eps2, WtF1, bua, WtF2, buu, WtF3, bc, out);
}

// Round 7
// 449.875 us; speedup vs baseline: 1.5842x; 1.5842x over previous
//
#include <hip/hip_runtime.h>

#define NN 50000
#define DD 64
#define EE 800000
#define BB 50
#define NMAXX 1000
#define CC 100

#define NBKT 391      // ceil(NN/128): bucket = dst>>7
#define BCAP 3072     // max edges per bucket (sort staging); mean 2048, +22 sigma
#define BCAPS 448     // per-sub-list capacity; mean 256, +12 sigma

typedef short short8 __attribute__((ext_vector_type(8)));
typedef float float4v __attribute__((ext_vector_type(4)));

__device__ __forceinline__ float rl(float v, int l) {
  return __int_as_float(__builtin_amdgcn_readlane(__float_as_int(v), l));
}
__device__ __forceinline__ short f2bf(float f) {
  unsigned u = __float_as_uint(f);
  unsigned r = (u + 0x7fffu + ((u >> 16) & 1u)) >> 16;
  return (short)r;
}
__device__ __forceinline__ unsigned pack2(float a, float b) {
  return (unsigned)(unsigned short)f2bf(a) |
         ((unsigned)(unsigned short)f2bf(b) << 16);
}

// B-fragment index for 16x16x32: frag[((ks*4+cb)*64+lane)*8+j] = W[k][n]
// k = ks*32 + (lane>>4)*8 + j, n = cb*16 + (lane&15)

// ---------- prep (fused): 8-way sub-counter bucket append + x->bf16 + W packs + msgup ----------
// Each (bucket, blockIdx&7) pair has its OWN 64B-line counter: same-address
// atomic serialization and cross-XCD line bounce both drop 8x vs r5.
__global__ __launch_bounds__(256) void k_prep(
    const int* __restrict__ ei, const float* __restrict__ x,
    const float* __restrict__ attr1,
    const float* __restrict__ Wma, const float* __restrict__ Wmu,
    const float* __restrict__ bmu, const float* __restrict__ Wua,
    const float* __restrict__ Wuu, const float* __restrict__ Wc,
    int* __restrict__ bcnt, short* __restrict__ xb,
    uint2* __restrict__ sdeB, short* __restrict__ msgupT,
    short* __restrict__ WtF, short* __restrict__ WtF1,
    short* __restrict__ WtF2, short* __restrict__ WtF3) {
  const int tid = threadIdx.x;
  if (blockIdx.x < EE / 256) {
    const int i = blockIdx.x * 256 + tid;          // [0, 800000)
    const int s = ei[i];
    const int d = ei[EE + i];
    const int bkt = d >> 7;                        // 0..390
    const int sub = blockIdx.x & 7;                // 8-way contention split
    int pos = atomicAdd(&bcnt[(bkt * 8 + sub) * 16], 1);
    if (pos < BCAPS)
      sdeB[((size_t)(bkt * 8 + sub)) * BCAPS + pos] =
          make_uint2((unsigned)s | ((unsigned)d << 16), (unsigned)i);
    {
      // NN*16 == EE: every thread converts 4 floats -> 4 bf16 (8B store)
      float4 xv = *(const float4*)&x[(size_t)i * 4];
      ((uint2*)xb)[i] = make_uint2(pack2(xv.x, xv.y), pack2(xv.z, xv.w));
    }
    if (i < 8192) {
      int j = i & 7, lane = (i >> 3) & 63, cbks = i >> 9;
      int cb = cbks & 3, ks = cbks >> 2;
      int k = ks * 32 + (lane >> 4) * 8 + j;
      int n = cb * 16 + (lane & 15);
      WtF[i]  = f2bf(Wma[k * 64 + n]);   // K=128
      WtF3[i] = f2bf(Wc[k * 64 + n]);    // K=128
      if (i < 4096) {                    // K=64 mats
        WtF1[i] = f2bf(Wua[k * 64 + n]);
        WtF2[i] = f2bf(Wuu[k * 64 + n]);
      }
    }
  } else {
    // ---- msgup branch ----
    __shared__ float Wl[64 * 64];
    for (int i = tid; i < 64 * 64; i += 256) Wl[i] = Wmu[i];
    __syncthreads();
    const int lane = tid & 63;
    const int row = (blockIdx.x - EE / 256) * 4 + (tid >> 6);   // b*100 + c
    float a = attr1[(size_t)row * 64 + lane];
    float acc = bmu[lane];
#pragma unroll 8
    for (int k = 0; k < 64; ++k)
      acc = fmaf(rl(a, k), Wl[k * 64 + lane], acc);
    const int b = row / 100, c = row - b * 100;
    msgupT[(size_t)b * 6400 + lane * 100 + c] = f2bf(fmaxf(acc, 0.f));
  }
}

// ---------- sort: concat 8 sub-lists, LDS counting sort -> globally dst-sorted sde ----------
__global__ __launch_bounds__(256) void k_sort(
    const uint2* __restrict__ sdeB, const int* __restrict__ bcnt,
    uint2* __restrict__ sde) {
  __shared__ uint2 Eb[BCAP];      // 24.6 KB
  __shared__ int lcnt[128];
  __shared__ int lpos[128];
  __shared__ int red[256];
  const int b = blockIdx.x, t = threadIdx.x;
  // base = sum over buckets j<b of their (clamped) totals
  int acc = 0;
  for (int j = t; j < b; j += 256) {
    int tj = 0;
#pragma unroll
    for (int s = 0; s < 8; ++s) {
      int c = bcnt[(j * 8 + s) * 16];
      tj += (c > BCAPS ? BCAPS : c);
    }
    acc += tj;
  }
  red[t] = acc;
  __syncthreads();
#pragma unroll
  for (int off = 128; off; off >>= 1) {
    if (t < off) red[t] += red[t + off];
    __syncthreads();
  }
  const int base = red[0];
  int ns[8];
  int ntot = 0;
#pragma unroll
  for (int s = 0; s < 8; ++s) {
    int c = bcnt[(b * 8 + s) * 16];
    ns[s] = (c > BCAPS ? BCAPS : c);
    ntot += ns[s];
  }
  if (ntot > BCAP) ntot = BCAP;
  if (t < 128) lcnt[t] = 0;
  __syncthreads();
  // load + histogram over in-bucket dst (dst & 127), concatenating sub-lists
  int off0 = 0;
#pragma unroll
  for (int s = 0; s < 8; ++s) {
    for (int i = t; i < ns[s]; i += 256) {
      int o = off0 + i;
      if (o < BCAP) {
        uint2 v = sdeB[((size_t)(b * 8 + s)) * BCAPS + i];
        Eb[o] = v;
        atomicAdd(&lcnt[(v.x >> 16) & 127], 1);
      }
    }
    off0 += ns[s];
  }
  __syncthreads();
  if (t < 128) {                  // exclusive scan over 128 counters
    int ssum = 0;
    for (int j = 0; j < t; ++j) ssum += lcnt[j];
    lpos[t] = ssum;
  }
  __syncthreads();
  for (int i = t; i < ntot; i += 256) {
    uint2 v = Eb[i];
    int p = atomicAdd(&lpos[(v.x >> 16) & 127], 1);
    sde[base + p] = v;
  }
}

// ---------- K2 (MFMA): agg_up = nc1 @ msg_up ----------
__global__ __launch_bounds__(256) void k_aggup(
    const float* __restrict__ nc1, const short* __restrict__ msgupT,
    float* __restrict__ aggup) {
  constexpr int LDA = 136;
  __shared__ float Ncf[64 * CC];
  __shared__ short A[64 * LDA];
  __shared__ short Wt[64 * LDA];
  const int b = blockIdx.x >> 4;
  const int tile = blockIdx.x & 15;
  const int i0 = tile * 64;
  const int tid = threadIdx.x;
  const float* ncb = nc1 + ((size_t)b * NMAXX + i0) * CC;
  for (int idx = tid; idx < 64 * CC; idx += 256) {
    int r = idx / CC;
    Ncf[idx] = (i0 + r < NMAXX) ? ncb[idx] : 0.f;
  }
  {
    const unsigned* src = (const unsigned*)(msgupT + (size_t)b * 6400);
    unsigned* dstw = (unsigned*)Wt;
    for (int i = tid; i < 64 * 50; i += 256) {
      int row = i / 50, cu = i - row * 50;
      dstw[row * 68 + cu] = src[i];
    }
    for (int i = tid; i < 64 * 14; i += 256) {
      int row = i / 14, cu = 50 + (i - row * 14);
      dstw[row * 68 + cu] = 0;
    }
  }
  __syncthreads();
  {
    const int row = tid >> 2, kp = tid & 3;
#pragma unroll
    for (int j = 0; j < 16; ++j) {
      int k = kp * 32 + 2 * j;
      unsigned u = 0;
      if (k < CC) {
        float2 v = *(const float2*)&Ncf[row * CC + k];
        u = pack2(v.x, v.y);
      }
      *(unsigned*)&A[row * LDA + k] = u;
    }
  }
  __syncthreads();
  const int lane = tid & 63;
  const int w = tid >> 6;
  const int m = lane & 15;
  const int koff = (lane >> 4) * 8;
  float4v acc[4];
#pragma unroll
  for (int cb = 0; cb < 4; ++cb) acc[cb] = (float4v)0.f;
#pragma unroll
  for (int ks = 0; ks < 4; ++ks) {
    short8 af = *(const short8*)&A[(w * 16 + m) * LDA + ks * 32 + koff];
#pragma unroll
    for (int cb = 0; cb < 4; ++cb) {
      short8 bf = *(const short8*)&Wt[(cb * 16 + m) * LDA + ks * 32 + koff];
      acc[cb] = __builtin_amdgcn_mfma_f32_16x16x32_bf16(af, bf, acc[cb], 0, 0, 0);
    }
  }
  const int rbase = (lane >> 4) * 4;
#pragma unroll
  for (int cb = 0; cb < 4; ++cb)
#pragma unroll
    for (int r = 0; r < 4; ++r) {
      int i = i0 + w * 16 + rbase + r;
      if (i < NMAXX)
        aggup[((size_t)b * NMAXX + i) * 64 + cb * 16 + m] = acc[cb][r];
    }
}

// ---------- K3 (MFMA): streaming edge MLP + segmented scatter (r5 proven) ----------
__global__ __launch_bounds__(256) void k_edge_mfma(
    const short* __restrict__ xb, const float* __restrict__ e,
    const uint2* __restrict__ sde, const short* __restrict__ WtF,
    const float* __restrict__ bma, float* __restrict__ agg) {
  __shared__ short WtL[8192];        // 16 KB fragment-ordered W_ma
  __shared__ float Cs[4][16][68];
  const int tid = threadIdx.x;
  // bijective XCD-chunked swizzle (nwg = 3125, not %8==0 -> m204 formula)
  const int nwg = gridDim.x;
  const int qq = nwg >> 3, rr = nwg & 7;
  const int xx = blockIdx.x & 7, oo = blockIdx.x >> 3;
  const int bid = (xx < rr ? xx * (qq + 1) : rr * (qq + 1) + (xx - rr) * qq) + oo;
  {
    const uint4* s = (const uint4*)WtF;
    uint4* d = (uint4*)WtL;
#pragma unroll
    for (int it = 0; it < 4; ++it) d[it * 256 + tid] = s[it * 256 + tid];
  }
  __syncthreads();
  const int lane = tid & 63;
  const int wv = tid >> 6;
  const int m = lane & 15;
  const int koff = (lane >> 4) * 8;
  float bias[4];
#pragma unroll
  for (int cb = 0; cb < 4; ++cb) bias[cb] = bma[cb * 16 + m];
  const int base = bid * 256 + wv * 64;
  const uint2 v0 = sde[base + m];
  const uint2 v1 = sde[base + 16 + m];
  const uint2 v2 = sde[base + 32 + m];
  const uint2 v3 = sde[base + 48 + m];
  int dprev = -1;
  float run = 0.f;
  float* aggL = agg + lane;

  short8 xA0, xA1, xB0, xB1;
  float4 fA0, fA1, fA2, fA3, fB0, fB1, fB2, fB3;

#define LOADC(vv, X0, X1, F0, F1, F2, F3) do {                      \
    const int src_ = (int)((vv).x & 0xffffu);                       \
    const float* er_ = e + (size_t)(vv).y * 64 + koff;              \
    X0 = *(const short8*)(xb + (size_t)src_ * 64 + koff);           \
    X1 = *(const short8*)(xb + (size_t)src_ * 64 + 32 + koff);      \
    F0 = *(const float4*)er_;                                       \
    F1 = *(const float4*)(er_ + 4);                                 \
    F2 = *(const float4*)(er_ + 32);                                \
    F3 = *(const float4*)(er_ + 36);                                \
  } while (0)

#define COMPUTE(vv, X0, X1, F0, F1, F2, F3) do {                    \
    union { unsigned u[4]; short8 s; } p2_, p3_;                    \
    p2_.u[0] = pack2(F0.x, F0.y); p2_.u[1] = pack2(F0.z, F0.w);     \
    p2_.u[2] = pack2(F1.x, F1.y); p2_.u[3] = pack2(F1.z, F1.w);     \
    p3_.u[0] = pack2(F2.x, F2.y); p3_.u[1] = pack2(F2.z, F2.w);     \
    p3_.u[2] = pack2(F3.x, F3.y); p3_.u[3] = pack2(F3.z, F3.w);     \
    float4v acc_[4];                                                \
    _Pragma("unroll")                                               \
    for (int cb = 0; cb < 4; ++cb) {                                \
      acc_[cb] = (float4v)(bias[cb]);  /* bias as MFMA C-in */      \
      short8 b0 = *(const short8*)&WtL[((0 * 4 + cb) * 64 + lane) * 8]; \
      short8 b1 = *(const short8*)&WtL[((1 * 4 + cb) * 64 + lane) * 8]; \
      short8 b2 = *(const short8*)&WtL[((2 * 4 + cb) * 64 + lane) * 8]; \
      short8 b3 = *(const short8*)&WtL[((3 * 4 + cb) * 64 + lane) * 8]; \
      acc_[cb] = __builtin_amdgcn_mfma_f32_16x16x32_bf16(X0, b0, acc_[cb], 0, 0, 0);    \
      acc_[cb] = __builtin_amdgcn_mfma_f32_16x16x32_bf16(X1, b1, acc_[cb], 0, 0, 0);    \
      acc_[cb] = __builtin_amdgcn_mfma_f32_16x16x32_bf16(p2_.s, b2, acc_[cb], 0, 0, 0); \
      acc_[cb] = __builtin_amdgcn_mfma_f32_16x16x32_bf16(p3_.s, b3, acc_[cb], 0, 0, 0); \
    }                                                               \
    const int rbase_ = (lane >> 4) * 4;                             \
    _Pragma("unroll")                                               \
    for (int cb = 0; cb < 4; ++cb)                                  \
      _Pragma("unroll")                                             \
      for (int r = 0; r < 4; ++r)                                   \
        Cs[wv][rbase_ + r][cb * 16 + m] = fmaxf(acc_[cb][r], 0.f);  \
    const int dst_ = (int)((vv).x >> 16);                           \
    _Pragma("unroll")                                               \
    for (int r = 0; r < 16; ++r) {                                  \
      int dr = __builtin_amdgcn_readlane(dst_, r);                  \
      float val = Cs[wv][r][lane];                                  \
      if (dr != dprev) {                                            \
        if (run != 0.f) atomicAdd(&aggL[(size_t)dprev * 64], run);  \
        run = 0.f;                                                  \
        dprev = dr;                                                 \
      }                                                             \
      run += val;                                                   \
    }                                                               \
  } while (0)

  LOADC(v0, xA0, xA1, fA0, fA1, fA2, fA3);
  LOADC(v1, xB0, xB1, fB0, fB1, fB2, fB3);
  COMPUTE(v0, xA0, xA1, fA0, fA1, fA2, fA3);
  LOADC(v2, xA0, xA1, fA0, fA1, fA2, fA3);
  COMPUTE(v1, xB0, xB1, fB0, fB1, fB2, fB3);
  LOADC(v3, xB0, xB1, fB0, fB1, fB2, fB3);
  COMPUTE(v2, xA0, xA1, fA0, fA1, fA2, fA3);
  COMPUTE(v3, xB0, xB1, fB0, fB1, fB2, fB3);
#undef LOADC
#undef COMPUTE
  if (run != 0.f) atomicAdd(&aggL[(size_t)dprev * 64], run);
}

// ---------- K4 (MFMA): fused epilogue, B-frags direct from global ----------
__global__ __launch_bounds__(256) void k_final(
    const float* __restrict__ x, const float* __restrict__ agg,
    const float* __restrict__ aggup, const int* __restrict__ xidx,
    const float* __restrict__ eps1, const float* __restrict__ eps2,
    const short* __restrict__ WtF1, const float* __restrict__ bua,
    const short* __restrict__ WtF2, const float* __restrict__ buu,
    const short* __restrict__ WtF3, const float* __restrict__ bc,
    float* __restrict__ out) {
  constexpr int LD1 = 72;
  constexpr int LD3 = 136;
  __shared__ short A1[64 * LD1];
  __shared__ short A2[64 * LD1];
  __shared__ short O[64 * LD3];
  const int tid = threadIdx.x;
  const float s1 = 1.f + eps1[0], s2 = 1.f + eps2[0];
  const int r0 = blockIdx.x * 64;
  {
    const int row = tid >> 2, kp = tid & 3;
    int g = r0 + row;
    if (g >= NN) g = NN - 1;
    const size_t xb_ = (size_t)g * 64 + kp * 16;
    const size_t ub = (size_t)xidx[g] * 64 + kp * 16;
#pragma unroll
    for (int j = 0; j < 4; ++j) {
      float4 xv = *(const float4*)&x[xb_ + j * 4];
      float4 av = *(const float4*)&agg[xb_ + j * 4];
      float4 uv = *(const float4*)&aggup[ub + j * 4];
      unsigned h1lo = pack2(av.x + s1 * xv.x, av.y + s1 * xv.y);
      unsigned h1hi = pack2(av.z + s1 * xv.z, av.w + s1 * xv.w);
      unsigned h2lo = pack2(uv.x + s2 * xv.x, uv.y + s2 * xv.y);
      unsigned h2hi = pack2(uv.z + s2 * xv.z, uv.w + s2 * xv.w);
      *(uint2*)&A1[row * LD1 + kp * 16 + j * 4] = make_uint2(h1lo, h1hi);
      *(uint2*)&A2[row * LD1 + kp * 16 + j * 4] = make_uint2(h2lo, h2hi);
    }
  }
  __syncthreads();
  const int lane = tid & 63;
  const int w = tid >> 6;
  const int m = lane & 15;
  const int koff = (lane >> 4) * 8;
  const int rbase = (lane >> 4) * 4;
  float4v acc1[4], acc2[4];
#pragma unroll
  for (int cb = 0; cb < 4; ++cb) { acc1[cb] = (float4v)0.f; acc2[cb] = (float4v)0.f; }
#pragma unroll
  for (int ks = 0; ks < 2; ++ks) {
    short8 a1 = *(const short8*)&A1[(w * 16 + m) * LD1 + ks * 32 + koff];
    short8 a2 = *(const short8*)&A2[(w * 16 + m) * LD1 + ks * 32 + koff];
#pragma unroll
    for (int cb = 0; cb < 4; ++cb) {
      short8 b1 = *(const short8*)&WtF1[((ks * 4 + cb) * 64 + lane) * 8];
      short8 b2 = *(const short8*)&WtF2[((ks * 4 + cb) * 64 + lane) * 8];
      acc1[cb] = __builtin_amdgcn_mfma_f32_16x16x32_bf16(a1, b1, acc1[cb], 0, 0, 0);
      acc2[cb] = __builtin_amdgcn_mfma_f32_16x16x32_bf16(a2, b2, acc2[cb], 0, 0, 0);
    }
  }
#pragma unroll
  for (int cb = 0; cb < 4; ++cb) {
    float bb1 = bua[cb * 16 + m];
    float bb2 = buu[cb * 16 + m];
#pragma unroll
    for (int r = 0; r < 4; ++r) {
      int rowL = w * 16 + rbase + r;
      O[rowL * LD3 + cb * 16 + m] = f2bf(fmaxf(acc1[cb][r] + bb1, 0.f));
      O[rowL * LD3 + 64 + cb * 16 + m] = f2bf(fmaxf(acc2[cb][r] + bb2, 0.f));
    }
  }
  __syncthreads();
  float4v acc3[4];
#pragma unroll
  for (int cb = 0; cb < 4; ++cb) acc3[cb] = (float4v)0.f;
#pragma unroll
  for (int ks = 0; ks < 4; ++ks) {
    short8 af = *(const short8*)&O[(w * 16 + m) * LD3 + ks * 32 + koff];
#pragma unroll
    for (int cb = 0; cb < 4; ++cb) {
      short8 bf = *(const short8*)&WtF3[((ks * 4 + cb) * 64 + lane) * 8];
      acc3[cb] = __builtin_amdgcn_mfma_f32_16x16x32_bf16(af, bf, acc3[cb], 0, 0, 0);
    }
  }
#pragma unroll
  for (int cb = 0; cb < 4; ++cb) {
    float bb = bc[cb * 16 + m];
#pragma unroll
    for (int r = 0; r < 4; ++r) {
      int g = r0 + w * 16 + rbase + r;
      if (g < NN)
        out[(size_t)g * 64 + cb * 16 + m] = acc3[cb][r] + bb;
    }
  }
}

extern "C" void kernel_launch(void* const* d_in, const int* in_sizes, int n_in,
                              void* d_out, int out_size, void* d_ws, size_t ws_size,
                              hipStream_t stream) {
  const float* x     = (const float*)d_in[0];
  const float* e     = (const float*)d_in[1];
  const int*   ei    = (const int*)d_in[2];
  const float* attr1 = (const float*)d_in[3];
  const float* nc1   = (const float*)d_in[4];
  const int*   xidx  = (const int*)d_in[5];
  const float* eps1  = (const float*)d_in[6];
  const float* eps2  = (const float*)d_in[7];
  const float* Wma   = (const float*)d_in[8];
  const float* bma   = (const float*)d_in[9];
  const float* Wmu   = (const float*)d_in[10];
  const float* bmu   = (const float*)d_in[11];
  const float* Wua   = (const float*)d_in[12];
  const float* bua   = (const float*)d_in[13];
  const float* Wuu   = (const float*)d_in[14];
  const float* buu   = (const float*)d_in[15];
  const float* Wc    = (const float*)d_in[16];
  const float* bc    = (const float*)d_in[17];
  float* out = (float*)d_out;

  float* agg    = (float*)d_ws;                      // [N*64] f32
  int*   bcnt   = (int*)(agg + (size_t)NN * 64);     // [NBKT*8*16] (memset w/ agg)
  float* aggup  = (float*)(bcnt + NBKT * 8 * 16);    // [N*64] f32
  short* msgupT = (short*)(aggup + (size_t)NN * 64); // [B*64*100] bf16
  short* xbuf   = msgupT + (size_t)BB * 6400;        // [N*64] bf16
  uint2* sdeB   = (uint2*)(xbuf + (size_t)NN * 64);  // [NBKT*8*BCAPS]
  uint2* sde    = sdeB + (size_t)NBKT * 8 * BCAPS;   // [E] sorted (src|dst<<16, eid)
  short* WtF    = (short*)(sde + EE);                // [8192]
  short* WtF1   = WtF + 8192;                        // [4096]
  short* WtF2   = WtF1 + 4096;                       // [4096]
  short* WtF3   = WtF2 + 4096;                       // [8192]

  hipMemsetAsync(agg, 0,
                 (size_t)NN * 64 * sizeof(float) + NBKT * 8 * 16 * sizeof(int),
                 stream);
  k_prep<<<dim3(EE / 256 + BB * CC / 4), dim3(256), 0, stream>>>(
      ei, x, attr1, Wma, Wmu, bmu, Wua, Wuu, Wc,
      bcnt, xbuf, sdeB, msgupT, WtF, WtF1, WtF2, WtF3);
  k_sort<<<dim3(NBKT), dim3(256), 0, stream>>>(sdeB, bcnt, sde);
  k_aggup<<<dim3(BB * 16), dim3(256), 0, stream>>>(nc1, msgupT, aggup);
  k_edge_mfma<<<dim3(EE / 256), dim3(256), 0, stream>>>(
      xbuf, e, sde, WtF, bma, agg);
  k_final<<<dim3((NN + 63) / 64), dim3(256), 0, stream>>>(
      x, agg, aggup, xidx, eps1, eps2, WtF1, bua, WtF2, buu, WtF3, bc, out);
}